// Round 1
// baseline (648.481 us; speedup 1.0000x reference)
//
#include <hip/hip_runtime.h>
#include <cstdint>

// ---------------------------------------------------------------------------
// TransformerEncoderBlock: LN1 -> QKV -> MHA -> proj+res -> LN2 -> FC1+GELU
//                          -> FC2+res.  bf16 MFMA compute, fp32 accum.
// Structure: m97-style 128x128x64 GEMM (global_load_lds width=16) + flash attn.
// ---------------------------------------------------------------------------

typedef unsigned short u16;
typedef short short8 __attribute__((ext_vector_type(8)));   // 8 bf16 = 4 VGPRs
typedef float floatx4 __attribute__((ext_vector_type(4)));  // MFMA C/D

#define GLB(p) ((const __attribute__((address_space(1))) void*)(p))
#define LDSP(p) ((__attribute__((address_space(3))) void*)(p))

__device__ __forceinline__ u16 f2bf(float f) {
    uint32_t u = __float_as_uint(f);
    u += 0x7fffu + ((u >> 16) & 1u);   // round-to-nearest-even
    return (u16)(u >> 16);
}

// ---------------- transpose + cast: W[K,N] f32 -> Wt[N,K] bf16 --------------
__global__ __launch_bounds__(256) void transpose_cast_kernel(
    const float* __restrict__ W, u16* __restrict__ Wt, int K, int N)
{
    __shared__ float tile[32][33];
    int n0 = blockIdx.x * 32, k0 = blockIdx.y * 32;
    int tx = threadIdx.x, ty = threadIdx.y; // block (32,8)
    #pragma unroll
    for (int i = 0; i < 4; ++i)
        tile[ty + i * 8][tx] = W[(size_t)(k0 + ty + i * 8) * N + n0 + tx];
    __syncthreads();
    #pragma unroll
    for (int i = 0; i < 4; ++i)
        Wt[(size_t)(n0 + ty + i * 8) * K + k0 + tx] = f2bf(tile[tx][ty + i * 8]);
}

// ---------------- LayerNorm: fp32 [rows,1024] -> bf16 ----------------------
__global__ __launch_bounds__(256) void ln_kernel(
    const float* __restrict__ x, const float* __restrict__ gw,
    const float* __restrict__ bw, u16* __restrict__ out)
{
    const int row = blockIdx.x, tid = threadIdx.x;
    float4 v = ((const float4*)(x + (size_t)row * 1024))[tid];
    float s  = v.x + v.y + v.z + v.w;
    float ss = v.x * v.x + v.y * v.y + v.z * v.z + v.w * v.w;
    #pragma unroll
    for (int off = 32; off > 0; off >>= 1) {
        s  += __shfl_down(s, off);
        ss += __shfl_down(ss, off);
    }
    __shared__ float red[8];
    if ((tid & 63) == 0) { red[tid >> 6] = s; red[4 + (tid >> 6)] = ss; }
    __syncthreads();
    float S  = red[0] + red[1] + red[2] + red[3];
    float SS = red[4] + red[5] + red[6] + red[7];
    float mu  = S * (1.0f / 1024.0f);
    float var = SS * (1.0f / 1024.0f) - mu * mu;
    float rs  = rsqrtf(var + 1e-5f);
    float4 g4 = ((const float4*)gw)[tid];
    float4 b4 = ((const float4*)bw)[tid];
    u16* o = out + (size_t)row * 1024 + tid * 4;
    o[0] = f2bf((v.x - mu) * rs * g4.x + b4.x);
    o[1] = f2bf((v.y - mu) * rs * g4.y + b4.y);
    o[2] = f2bf((v.z - mu) * rs * g4.z + b4.z);
    o[3] = f2bf((v.w - mu) * rs * g4.w + b4.w);
}

// ---------------- GEMM: C[M,N] = A[M,K](bf16) x Bt[N,K](bf16)^T ------------
// 128x128 tile, BK=64, 4 waves in 2x2, 4x4 16x16 C-tiles per wave (m97 shape).
#define MODE_BF16      0   // out bf16 = acc + bias
#define MODE_BF16_GELU 1   // out bf16 = gelu(acc + bias), exact erf gelu
#define MODE_F32_RES   2   // out f32  = acc + bias + res

template<int MODE>
__global__ __launch_bounds__(256) void gemm_bt_kernel(
    const u16* __restrict__ A, const u16* __restrict__ Bt,
    const float* __restrict__ bias, const float* __restrict__ res,
    void* __restrict__ outv, int M, int N, int K)
{
    __shared__ __attribute__((aligned(16))) u16 As[128 * 64];
    __shared__ __attribute__((aligned(16))) u16 Bs[128 * 64];
    const int tid = threadIdx.x;
    const int wave = tid >> 6, lane = tid & 63;
    const int lg = lane >> 4, lc = lane & 15;
    const int m0 = blockIdx.y * 128, n0 = blockIdx.x * 128;
    const int wr = wave >> 1, wc = wave & 1;

    floatx4 acc[4][4];
    #pragma unroll
    for (int i = 0; i < 4; ++i)
        #pragma unroll
        for (int j = 0; j < 4; ++j) acc[i][j] = floatx4{0.f, 0.f, 0.f, 0.f};

    // staging: per thread 4 issues of 16B each for A and B tiles
    const u16* Ag = A  + (size_t)(m0 + wave * 32 + (lane >> 3)) * K + (lane & 7) * 8;
    const u16* Bg = Bt + (size_t)(n0 + wave * 32 + (lane >> 3)) * K + (lane & 7) * 8;
    u16* Asw = &As[wave * 4 * 512];   // wave-uniform LDS bases
    u16* Bsw = &Bs[wave * 4 * 512];

    const int kiters = K >> 6;
    for (int kt = 0; kt < kiters; ++kt) {
        #pragma unroll
        for (int j = 0; j < 4; ++j) {
            __builtin_amdgcn_global_load_lds(GLB(Ag + (size_t)j * 8 * K), LDSP(Asw + j * 512), 16, 0, 0);
            __builtin_amdgcn_global_load_lds(GLB(Bg + (size_t)j * 8 * K), LDSP(Bsw + j * 512), 16, 0, 0);
        }
        Ag += 64; Bg += 64;
        __syncthreads();
        #pragma unroll
        for (int ks = 0; ks < 2; ++ks) {
            short8 fa[4], fb[4];
            #pragma unroll
            for (int mt = 0; mt < 4; ++mt)
                fa[mt] = *(const short8*)&As[(wr * 64 + mt * 16 + lc) * 64 + ks * 32 + lg * 8];
            #pragma unroll
            for (int nt = 0; nt < 4; ++nt)
                fb[nt] = *(const short8*)&Bs[(wc * 64 + nt * 16 + lc) * 64 + ks * 32 + lg * 8];
            #pragma unroll
            for (int mt = 0; mt < 4; ++mt)
                #pragma unroll
                for (int nt = 0; nt < 4; ++nt)
                    acc[mt][nt] = __builtin_amdgcn_mfma_f32_16x16x32_bf16(fa[mt], fb[nt], acc[mt][nt], 0, 0, 0);
        }
        __syncthreads();
    }

    // epilogue: C/D layout col=lane&15, row=(lane>>4)*4+reg (HW-verified)
    #pragma unroll
    for (int mt = 0; mt < 4; ++mt) {
        #pragma unroll
        for (int nt = 0; nt < 4; ++nt) {
            const int col = n0 + wc * 64 + nt * 16 + lc;
            const float bv = bias[col];
            #pragma unroll
            for (int r = 0; r < 4; ++r) {
                const int row = m0 + wr * 64 + mt * 16 + lg * 4 + r;
                float v = acc[mt][nt][r] + bv;
                if (MODE == MODE_BF16) {
                    ((u16*)outv)[(size_t)row * N + col] = f2bf(v);
                } else if (MODE == MODE_BF16_GELU) {
                    float gl = 0.5f * v * (1.0f + erff(v * 0.70710678118f));
                    ((u16*)outv)[(size_t)row * N + col] = f2bf(gl);
                } else {
                    ((float*)outv)[(size_t)row * N + col] = v + res[(size_t)row * N + col];
                }
            }
        }
    }
}

// ---------------- Flash attention: qkv[8,1024,3072] bf16 -> out bf16 -------
// grid: b*16*16 blocks; block = (b, head, 64-row Q tile); 4 waves x 16 q-rows.
__global__ __launch_bounds__(256) void attn_kernel(
    const u16* __restrict__ qkv, u16* __restrict__ out)
{
    const int blk = blockIdx.x;
    const int qt = blk & 15;
    const int h  = (blk >> 4) & 15;
    const int b  = blk >> 8;
    const int tid = threadIdx.x, wave = tid >> 6, lane = tid & 63;
    const int lg = lane >> 4, lc = lane & 15;

    __shared__ __attribute__((aligned(16))) u16 Qs[64 * 64];
    __shared__ __attribute__((aligned(16))) u16 Ks[64 * 64];
    __shared__ __attribute__((aligned(16))) u16 Vts[64 * 80]; // [d][key], pad->16B rows
    __shared__ __attribute__((aligned(16))) u16 Ps[64 * 64];  // [q][key]

    const int q0 = qt * 64;
    const size_t hb = ((size_t)b * 1024) * 3072 + h * 64;

    // stage Q tile [64 q][64 d]
    {
        const u16* Qg = qkv + hb + (size_t)(q0 + wave * 16 + (lane >> 3)) * 3072 + (lane & 7) * 8;
        u16* Qw = &Qs[wave * 2 * 512];
        __builtin_amdgcn_global_load_lds(GLB(Qg), LDSP(Qw), 16, 0, 0);
        __builtin_amdgcn_global_load_lds(GLB(Qg + (size_t)8 * 3072), LDSP(Qw + 512), 16, 0, 0);
    }
    __syncthreads();
    short8 aq[2];
    aq[0] = *(const short8*)&Qs[(wave * 16 + lc) * 64 + lg * 8];
    aq[1] = *(const short8*)&Qs[(wave * 16 + lc) * 64 + 32 + lg * 8];

    floatx4 o[4];
    #pragma unroll
    for (int dt = 0; dt < 4; ++dt) o[dt] = floatx4{0.f, 0.f, 0.f, 0.f};
    float mprev[4] = {-INFINITY, -INFINITY, -INFINITY, -INFINITY};
    float lsum[4]  = {0.f, 0.f, 0.f, 0.f};
    const float scale = 0.125f; // 1/sqrt(64)

    for (int kt = 0; kt < 16; ++kt) {
        __syncthreads();  // prior-iter readers of Ks/Vts/Ps done
        // stage K tile [64 key][64 d]
        {
            const u16* Kg = qkv + hb + 1024 +
                (size_t)(kt * 64 + wave * 16 + (lane >> 3)) * 3072 + (lane & 7) * 8;
            u16* Kw = &Ks[wave * 2 * 512];
            __builtin_amdgcn_global_load_lds(GLB(Kg), LDSP(Kw), 16, 0, 0);
            __builtin_amdgcn_global_load_lds(GLB(Kg + (size_t)8 * 3072), LDSP(Kw + 512), 16, 0, 0);
        }
        // stage V transposed -> Vts[d][key]
        {
            const int key = tid >> 2, d0 = (tid & 3) * 16;
            const uint4* vp = (const uint4*)(qkv + hb + 2048 + (size_t)(kt * 64 + key) * 3072 + d0);
            uint4 va = vp[0], vb = vp[1];
            u16 e[16];
            *(uint4*)(e) = va; *(uint4*)(e + 8) = vb;
            #pragma unroll
            for (int i = 0; i < 16; ++i)
                Vts[(d0 + i) * 80 + key] = e[i];
        }
        __syncthreads();

        // S = Q K^T * scale   (per wave: 16 q-rows x 64 keys)
        floatx4 s[4];
        #pragma unroll
        for (int nt = 0; nt < 4; ++nt) s[nt] = floatx4{0.f, 0.f, 0.f, 0.f};
        #pragma unroll
        for (int ks = 0; ks < 2; ++ks)
            #pragma unroll
            for (int nt = 0; nt < 4; ++nt) {
                short8 fk = *(const short8*)&Ks[(nt * 16 + lc) * 64 + ks * 32 + lg * 8];
                s[nt] = __builtin_amdgcn_mfma_f32_16x16x32_bf16(aq[ks], fk, s[nt], 0, 0, 0);
            }
        #pragma unroll
        for (int nt = 0; nt < 4; ++nt) s[nt] *= scale;

        // online softmax: row reductions across the 16 lanes of a quad-group
        float aexp[4];
        #pragma unroll
        for (int r = 0; r < 4; ++r) {
            float m = fmaxf(fmaxf(s[0][r], s[1][r]), fmaxf(s[2][r], s[3][r]));
            #pragma unroll
            for (int off = 8; off > 0; off >>= 1)
                m = fmaxf(m, __shfl_xor(m, off));
            float mn = fmaxf(mprev[r], m);
            aexp[r] = __expf(mprev[r] - mn);
            mprev[r] = mn;
        }
        float rs[4] = {0.f, 0.f, 0.f, 0.f};
        #pragma unroll
        for (int nt = 0; nt < 4; ++nt)
            #pragma unroll
            for (int r = 0; r < 4; ++r) {
                float p = __expf(s[nt][r] - mprev[r]);
                rs[r] += p;
                Ps[(wave * 16 + lg * 4 + r) * 64 + nt * 16 + lc] = f2bf(p);
            }
        #pragma unroll
        for (int r = 0; r < 4; ++r) {
            #pragma unroll
            for (int off = 8; off > 0; off >>= 1)
                rs[r] += __shfl_xor(rs[r], off);
            lsum[r] = lsum[r] * aexp[r] + rs[r];
        }
        #pragma unroll
        for (int dt = 0; dt < 4; ++dt)
            #pragma unroll
            for (int r = 0; r < 4; ++r)
                o[dt][r] *= aexp[r];
        __syncthreads();  // Ps visible

        // O += P V   (A = P from LDS, B = Vt[d][key])
        #pragma unroll
        for (int ks = 0; ks < 2; ++ks) {
            short8 ap = *(const short8*)&Ps[(wave * 16 + lc) * 64 + ks * 32 + lg * 8];
            #pragma unroll
            for (int dt = 0; dt < 4; ++dt) {
                short8 fv = *(const short8*)&Vts[(dt * 16 + lc) * 80 + ks * 32 + lg * 8];
                o[dt] = __builtin_amdgcn_mfma_f32_16x16x32_bf16(ap, fv, o[dt], 0, 0, 0);
            }
        }
    }

    // epilogue: out[b, q, h*64 + d] = O / l
    #pragma unroll
    for (int dt = 0; dt < 4; ++dt)
        #pragma unroll
        for (int r = 0; r < 4; ++r) {
            const int q = q0 + wave * 16 + lg * 4 + r;
            float val = o[dt][r] / lsum[r];
            out[((size_t)b * 1024 + q) * 1024 + h * 64 + dt * 16 + lc] = f2bf(val);
        }
}

// ---------------------------------------------------------------------------
extern "C" void kernel_launch(void* const* d_in, const int* in_sizes, int n_in,
                              void* d_out, int out_size, void* d_ws, size_t ws_size,
                              hipStream_t stream)
{
    const float* x      = (const float*)d_in[0];
    const float* ln1_g  = (const float*)d_in[1];
    const float* ln1_b  = (const float*)d_in[2];
    const float* w_qkv  = (const float*)d_in[3];
    const float* b_qkv  = (const float*)d_in[4];
    const float* w_proj = (const float*)d_in[5];
    const float* b_proj = (const float*)d_in[6];
    const float* ln2_g  = (const float*)d_in[7];
    const float* ln2_b  = (const float*)d_in[8];
    const float* w_fc1  = (const float*)d_in[9];
    const float* b_fc1  = (const float*)d_in[10];
    const float* w_fc2  = (const float*)d_in[11];
    const float* b_fc2  = (const float*)d_in[12];
    float* outp = (float*)d_out;

    char* ws = (char*)d_ws;
    size_t off = 0;
    auto alloc = [&](size_t bytes) { void* p = ws + off; off += (bytes + 255) & ~(size_t)255; return p; };
    u16*  wqkvT  = (u16*)alloc((size_t)3072 * 1024 * 2);
    u16*  wprojT = (u16*)alloc((size_t)1024 * 1024 * 2);
    u16*  wfc1T  = (u16*)alloc((size_t)4096 * 1024 * 2);
    u16*  wfc2T  = (u16*)alloc((size_t)1024 * 4096 * 2);
    u16*  hbuf   = (u16*)alloc((size_t)8192 * 1024 * 2);  // LN1 out, later LN2 out
    u16*  big    = (u16*)alloc((size_t)8192 * 4096 * 2);  // qkv, later mlp hidden
    u16*  attno  = (u16*)alloc((size_t)8192 * 1024 * 2);
    float* x2    = (float*)alloc((size_t)8192 * 1024 * 4);

    dim3 tb(32, 8);
    transpose_cast_kernel<<<dim3(3072 / 32, 1024 / 32), tb, 0, stream>>>(w_qkv,  wqkvT,  1024, 3072);
    transpose_cast_kernel<<<dim3(1024 / 32, 1024 / 32), tb, 0, stream>>>(w_proj, wprojT, 1024, 1024);
    transpose_cast_kernel<<<dim3(4096 / 32, 1024 / 32), tb, 0, stream>>>(w_fc1,  wfc1T,  1024, 4096);
    transpose_cast_kernel<<<dim3(1024 / 32, 4096 / 32), tb, 0, stream>>>(w_fc2,  wfc2T,  4096, 1024);

    ln_kernel<<<8192, 256, 0, stream>>>(x, ln1_g, ln1_b, hbuf);
    gemm_bt_kernel<MODE_BF16><<<dim3(3072 / 128, 8192 / 128), 256, 0, stream>>>(
        hbuf, wqkvT, b_qkv, nullptr, big, 8192, 3072, 1024);
    attn_kernel<<<2048, 256, 0, stream>>>(big, attno);
    gemm_bt_kernel<MODE_F32_RES><<<dim3(1024 / 128, 8192 / 128), 256, 0, stream>>>(
        attno, wprojT, b_proj, x, x2, 8192, 1024, 1024);
    ln_kernel<<<8192, 256, 0, stream>>>(x2, ln2_g, ln2_b, hbuf);
    gemm_bt_kernel<MODE_BF16_GELU><<<dim3(4096 / 128, 8192 / 128), 256, 0, stream>>>(
        hbuf, wfc1T, b_fc1, nullptr, big, 8192, 4096, 1024);
    gemm_bt_kernel<MODE_F32_RES><<<dim3(1024 / 128, 8192 / 128), 256, 0, stream>>>(
        big, wfc2T, b_fc2, x2, outp, 8192, 1024, 4096);
}

// Round 2
// 572.896 us; speedup vs baseline: 1.1319x; 1.1319x over previous
//
#include <hip/hip_runtime.h>
#include <cstdint>

// ---------------------------------------------------------------------------
// TransformerEncoderBlock: LN1 -> QKV -> MHA -> proj+res -> LN2 -> FC1+GELU
//                          -> FC2+res.  bf16 MFMA compute, fp32 accum.
// R2: XOR-swizzled LDS chunks (phys_chunk = logical ^ (row&7)) to kill the
//     16-way bank conflicts of the 128B-stride row layout. Swizzle applied
//     at the global-source side for global_load_lds staging.
// ---------------------------------------------------------------------------

typedef unsigned short u16;
typedef short short8 __attribute__((ext_vector_type(8)));   // 8 bf16 = 4 VGPRs
typedef float floatx4 __attribute__((ext_vector_type(4)));  // MFMA C/D

#define GLB(p) ((const __attribute__((address_space(1))) void*)(p))
#define LDSP(p) ((__attribute__((address_space(3))) void*)(p))

__device__ __forceinline__ u16 f2bf(float f) {
    uint32_t u = __float_as_uint(f);
    u += 0x7fffu + ((u >> 16) & 1u);   // round-to-nearest-even
    return (u16)(u >> 16);
}

// ---------------- transpose + cast: W[K,N] f32 -> Wt[N,K] bf16 --------------
__global__ __launch_bounds__(256) void transpose_cast_kernel(
    const float* __restrict__ W, u16* __restrict__ Wt, int K, int N)
{
    __shared__ float tile[32][33];
    int n0 = blockIdx.x * 32, k0 = blockIdx.y * 32;
    int tx = threadIdx.x, ty = threadIdx.y; // block (32,8)
    #pragma unroll
    for (int i = 0; i < 4; ++i)
        tile[ty + i * 8][tx] = W[(size_t)(k0 + ty + i * 8) * N + n0 + tx];
    __syncthreads();
    #pragma unroll
    for (int i = 0; i < 4; ++i)
        Wt[(size_t)(n0 + ty + i * 8) * K + k0 + tx] = f2bf(tile[tx][ty + i * 8]);
}

// ---------------- LayerNorm: fp32 [rows,1024] -> bf16 ----------------------
__global__ __launch_bounds__(256) void ln_kernel(
    const float* __restrict__ x, const float* __restrict__ gw,
    const float* __restrict__ bw, u16* __restrict__ out)
{
    const int row = blockIdx.x, tid = threadIdx.x;
    float4 v = ((const float4*)(x + (size_t)row * 1024))[tid];
    float s  = v.x + v.y + v.z + v.w;
    float ss = v.x * v.x + v.y * v.y + v.z * v.z + v.w * v.w;
    #pragma unroll
    for (int off = 32; off > 0; off >>= 1) {
        s  += __shfl_down(s, off);
        ss += __shfl_down(ss, off);
    }
    __shared__ float red[8];
    if ((tid & 63) == 0) { red[tid >> 6] = s; red[4 + (tid >> 6)] = ss; }
    __syncthreads();
    float S  = red[0] + red[1] + red[2] + red[3];
    float SS = red[4] + red[5] + red[6] + red[7];
    float mu  = S * (1.0f / 1024.0f);
    float var = SS * (1.0f / 1024.0f) - mu * mu;
    float rs  = rsqrtf(var + 1e-5f);
    float4 g4 = ((const float4*)gw)[tid];
    float4 b4 = ((const float4*)bw)[tid];
    u16* o = out + (size_t)row * 1024 + tid * 4;
    o[0] = f2bf((v.x - mu) * rs * g4.x + b4.x);
    o[1] = f2bf((v.y - mu) * rs * g4.y + b4.y);
    o[2] = f2bf((v.z - mu) * rs * g4.z + b4.z);
    o[3] = f2bf((v.w - mu) * rs * g4.w + b4.w);
}

// ---------------- GEMM: C[M,N] = A[M,K](bf16) x Bt[N,K](bf16)^T ------------
// 128x128 tile, BK=64, 4 waves in 2x2, 4x4 16x16 C-tiles per wave.
// LDS rows: 8 chunks of 16B; physical chunk = logical ^ (row & 7).
#define MODE_BF16      0   // out bf16 = acc + bias
#define MODE_BF16_GELU 1   // out bf16 = gelu(acc + bias), exact erf gelu
#define MODE_F32_RES   2   // out f32  = acc + bias + res

template<int MODE>
__global__ __launch_bounds__(256) void gemm_bt_kernel(
    const u16* __restrict__ A, const u16* __restrict__ Bt,
    const float* __restrict__ bias, const float* __restrict__ res,
    void* __restrict__ outv, int M, int N, int K)
{
    __shared__ __attribute__((aligned(16))) u16 As[128 * 64];
    __shared__ __attribute__((aligned(16))) u16 Bs[128 * 64];
    const int tid = threadIdx.x;
    const int wave = tid >> 6, lane = tid & 63;
    const int lg = lane >> 4, lc = lane & 15;
    const int m0 = blockIdx.y * 128, n0 = blockIdx.x * 128;
    const int wr = wave >> 1, wc = wave & 1;

    floatx4 acc[4][4];
    #pragma unroll
    for (int i = 0; i < 4; ++i)
        #pragma unroll
        for (int j = 0; j < 4; ++j) acc[i][j] = floatx4{0.f, 0.f, 0.f, 0.f};

    // staging: lane L fills LDS slot (row = L>>3, chunk = L&7) of its j-group;
    // source chunk is XOR-swizzled so LDS slot (r,c) holds logical chunk c^(r&7).
    const int srow = lane >> 3;                        // row & 7 within 8-row group
    const int schunk = (lane & 7) ^ srow;              // swizzled global chunk
    const u16* Ag = A  + (size_t)(m0 + wave * 32 + srow) * K + schunk * 8;
    const u16* Bg = Bt + (size_t)(n0 + wave * 32 + srow) * K + schunk * 8;
    u16* Asw = &As[wave * 4 * 512];   // wave-uniform LDS bases
    u16* Bsw = &Bs[wave * 4 * 512];

    const int kiters = K >> 6;
    for (int kt = 0; kt < kiters; ++kt) {
        #pragma unroll
        for (int j = 0; j < 4; ++j) {
            __builtin_amdgcn_global_load_lds(GLB(Ag + (size_t)j * 8 * K), LDSP(Asw + j * 512), 16, 0, 0);
            __builtin_amdgcn_global_load_lds(GLB(Bg + (size_t)j * 8 * K), LDSP(Bsw + j * 512), 16, 0, 0);
        }
        Ag += 64; Bg += 64;
        __syncthreads();
        #pragma unroll
        for (int ks = 0; ks < 2; ++ks) {
            short8 fa[4], fb[4];
            #pragma unroll
            for (int mt = 0; mt < 4; ++mt)
                fa[mt] = *(const short8*)&As[(wr * 64 + mt * 16 + lc) * 64 +
                                             (((ks * 4 + lg) ^ (lc & 7)) * 8)];
            #pragma unroll
            for (int nt = 0; nt < 4; ++nt)
                fb[nt] = *(const short8*)&Bs[(wc * 64 + nt * 16 + lc) * 64 +
                                             (((ks * 4 + lg) ^ (lc & 7)) * 8)];
            #pragma unroll
            for (int mt = 0; mt < 4; ++mt)
                #pragma unroll
                for (int nt = 0; nt < 4; ++nt)
                    acc[mt][nt] = __builtin_amdgcn_mfma_f32_16x16x32_bf16(fa[mt], fb[nt], acc[mt][nt], 0, 0, 0);
        }
        __syncthreads();
    }

    // epilogue: C/D layout col=lane&15, row=(lane>>4)*4+reg (HW-verified)
    #pragma unroll
    for (int mt = 0; mt < 4; ++mt) {
        #pragma unroll
        for (int nt = 0; nt < 4; ++nt) {
            const int col = n0 + wc * 64 + nt * 16 + lc;
            const float bv = bias[col];
            #pragma unroll
            for (int r = 0; r < 4; ++r) {
                const int row = m0 + wr * 64 + mt * 16 + lg * 4 + r;
                float v = acc[mt][nt][r] + bv;
                if (MODE == MODE_BF16) {
                    ((u16*)outv)[(size_t)row * N + col] = f2bf(v);
                } else if (MODE == MODE_BF16_GELU) {
                    float gl = 0.5f * v * (1.0f + erff(v * 0.70710678118f));
                    ((u16*)outv)[(size_t)row * N + col] = f2bf(gl);
                } else {
                    ((float*)outv)[(size_t)row * N + col] = v + res[(size_t)row * N + col];
                }
            }
        }
    }
}

// ---------------- Flash attention: qkv[8,1024,3072] bf16 -> out bf16 -------
// grid: b*16*16 blocks; block = (b, head, 64-row Q tile); 4 waves x 16 q-rows.
// Same XOR chunk swizzle on all LDS tiles.
__global__ __launch_bounds__(256) void attn_kernel(
    const u16* __restrict__ qkv, u16* __restrict__ out)
{
    const int blk = blockIdx.x;
    const int qt = blk & 15;
    const int h  = (blk >> 4) & 15;
    const int b  = blk >> 8;
    const int tid = threadIdx.x, wave = tid >> 6, lane = tid & 63;
    const int lg = lane >> 4, lc = lane & 15;

    __shared__ __attribute__((aligned(16))) u16 Qs[64 * 64];
    __shared__ __attribute__((aligned(16))) u16 Ks[64 * 64];
    __shared__ __attribute__((aligned(16))) u16 Vts[64 * 64]; // [d][key], swizzled
    __shared__ __attribute__((aligned(16))) u16 Ps[64 * 64];  // [q][key], swizzled

    const int q0 = qt * 64;
    const size_t hb = ((size_t)b * 1024) * 3072 + h * 64;
    const int srow = lane >> 3;
    const int schunk = (lane & 7) ^ srow;   // swizzled source chunk

    // stage Q tile [64 q][64 d], swizzled
    {
        const u16* Qg = qkv + hb + (size_t)(q0 + wave * 16 + srow) * 3072 + schunk * 8;
        u16* Qw = &Qs[wave * 2 * 512];
        __builtin_amdgcn_global_load_lds(GLB(Qg), LDSP(Qw), 16, 0, 0);
        __builtin_amdgcn_global_load_lds(GLB(Qg + (size_t)8 * 3072), LDSP(Qw + 512), 16, 0, 0);
    }
    __syncthreads();
    short8 aq[2];
    aq[0] = *(const short8*)&Qs[(wave * 16 + lc) * 64 + (((0 + lg) ^ (lc & 7)) * 8)];
    aq[1] = *(const short8*)&Qs[(wave * 16 + lc) * 64 + (((4 + lg) ^ (lc & 7)) * 8)];

    floatx4 o[4];
    #pragma unroll
    for (int dt = 0; dt < 4; ++dt) o[dt] = floatx4{0.f, 0.f, 0.f, 0.f};
    float mprev[4] = {-INFINITY, -INFINITY, -INFINITY, -INFINITY};
    float lsum[4]  = {0.f, 0.f, 0.f, 0.f};
    const float scale = 0.125f; // 1/sqrt(64)

    for (int kt = 0; kt < 16; ++kt) {
        __syncthreads();  // prior-iter readers of Ks/Vts/Ps done
        // stage K tile [64 key][64 d], swizzled
        {
            const u16* Kg = qkv + hb + 1024 +
                (size_t)(kt * 64 + wave * 16 + srow) * 3072 + schunk * 8;
            u16* Kw = &Ks[wave * 2 * 512];
            __builtin_amdgcn_global_load_lds(GLB(Kg), LDSP(Kw), 16, 0, 0);
            __builtin_amdgcn_global_load_lds(GLB(Kg + (size_t)8 * 3072), LDSP(Kw + 512), 16, 0, 0);
        }
        // stage V transposed -> Vts[d][key], swizzled chunks
        {
            const int key = tid >> 2, d0 = (tid & 3) * 16;
            const int kc = key >> 3, ke = key & 7;
            const uint4* vp = (const uint4*)(qkv + hb + 2048 + (size_t)(kt * 64 + key) * 3072 + d0);
            uint4 va = vp[0], vb = vp[1];
            u16 e[16];
            *(uint4*)(e) = va; *(uint4*)(e + 8) = vb;
            #pragma unroll
            for (int i = 0; i < 16; ++i) {
                const int d = d0 + i;
                Vts[d * 64 + ((kc ^ (d & 7)) * 8) + ke] = e[i];
            }
        }
        __syncthreads();

        // S = Q K^T * scale   (per wave: 16 q-rows x 64 keys)
        floatx4 s[4];
        #pragma unroll
        for (int nt = 0; nt < 4; ++nt) s[nt] = floatx4{0.f, 0.f, 0.f, 0.f};
        #pragma unroll
        for (int ks = 0; ks < 2; ++ks)
            #pragma unroll
            for (int nt = 0; nt < 4; ++nt) {
                short8 fk = *(const short8*)&Ks[(nt * 16 + lc) * 64 +
                                                (((ks * 4 + lg) ^ (lc & 7)) * 8)];
                s[nt] = __builtin_amdgcn_mfma_f32_16x16x32_bf16(aq[ks], fk, s[nt], 0, 0, 0);
            }
        #pragma unroll
        for (int nt = 0; nt < 4; ++nt) s[nt] *= scale;

        // online softmax: row reductions across the 16 lanes of a quad-group
        float aexp[4];
        #pragma unroll
        for (int r = 0; r < 4; ++r) {
            float m = fmaxf(fmaxf(s[0][r], s[1][r]), fmaxf(s[2][r], s[3][r]));
            #pragma unroll
            for (int off = 8; off > 0; off >>= 1)
                m = fmaxf(m, __shfl_xor(m, off));
            float mn = fmaxf(mprev[r], m);
            aexp[r] = __expf(mprev[r] - mn);
            mprev[r] = mn;
        }
        float rs[4] = {0.f, 0.f, 0.f, 0.f};
        #pragma unroll
        for (int nt = 0; nt < 4; ++nt)
            #pragma unroll
            for (int r = 0; r < 4; ++r) {
                float p = __expf(s[nt][r] - mprev[r]);
                rs[r] += p;
                const int q = wave * 16 + lg * 4 + r;
                const int colc = nt * 2 + (lc >> 3);  // logical chunk of column
                Ps[q * 64 + ((colc ^ (q & 7)) * 8) + (lc & 7)] = f2bf(p);
            }
        #pragma unroll
        for (int r = 0; r < 4; ++r) {
            #pragma unroll
            for (int off = 8; off > 0; off >>= 1)
                rs[r] += __shfl_xor(rs[r], off);
            lsum[r] = lsum[r] * aexp[r] + rs[r];
        }
        #pragma unroll
        for (int dt = 0; dt < 4; ++dt)
            #pragma unroll
            for (int r = 0; r < 4; ++r)
                o[dt][r] *= aexp[r];
        __syncthreads();  // Ps visible

        // O += P V   (A = P from LDS, B = Vt[d][key])
        #pragma unroll
        for (int ks = 0; ks < 2; ++ks) {
            short8 ap = *(const short8*)&Ps[(wave * 16 + lc) * 64 +
                                            (((ks * 4 + lg) ^ (lc & 7)) * 8)];
            #pragma unroll
            for (int dt = 0; dt < 4; ++dt) {
                short8 fv = *(const short8*)&Vts[(dt * 16 + lc) * 64 +
                                                 (((ks * 4 + lg) ^ (lc & 7)) * 8)];
                o[dt] = __builtin_amdgcn_mfma_f32_16x16x32_bf16(ap, fv, o[dt], 0, 0, 0);
            }
        }
    }

    // epilogue: out[b, q, h*64 + d] = O / l
    #pragma unroll
    for (int dt = 0; dt < 4; ++dt)
        #pragma unroll
        for (int r = 0; r < 4; ++r) {
            const int q = q0 + wave * 16 + lg * 4 + r;
            float val = o[dt][r] / lsum[r];
            out[((size_t)b * 1024 + q) * 1024 + h * 64 + dt * 16 + lc] = f2bf(val);
        }
}

// ---------------------------------------------------------------------------
extern "C" void kernel_launch(void* const* d_in, const int* in_sizes, int n_in,
                              void* d_out, int out_size, void* d_ws, size_t ws_size,
                              hipStream_t stream)
{
    const float* x      = (const float*)d_in[0];
    const float* ln1_g  = (const float*)d_in[1];
    const float* ln1_b  = (const float*)d_in[2];
    const float* w_qkv  = (const float*)d_in[3];
    const float* b_qkv  = (const float*)d_in[4];
    const float* w_proj = (const float*)d_in[5];
    const float* b_proj = (const float*)d_in[6];
    const float* ln2_g  = (const float*)d_in[7];
    const float* ln2_b  = (const float*)d_in[8];
    const float* w_fc1  = (const float*)d_in[9];
    const float* b_fc1  = (const float*)d_in[10];
    const float* w_fc2  = (const float*)d_in[11];
    const float* b_fc2  = (const float*)d_in[12];
    float* outp = (float*)d_out;

    char* ws = (char*)d_ws;
    size_t off = 0;
    auto alloc = [&](size_t bytes) { void* p = ws + off; off += (bytes + 255) & ~(size_t)255; return p; };
    u16*  wqkvT  = (u16*)alloc((size_t)3072 * 1024 * 2);
    u16*  wprojT = (u16*)alloc((size_t)1024 * 1024 * 2);
    u16*  wfc1T  = (u16*)alloc((size_t)4096 * 1024 * 2);
    u16*  wfc2T  = (u16*)alloc((size_t)1024 * 4096 * 2);
    u16*  hbuf   = (u16*)alloc((size_t)8192 * 1024 * 2);  // LN1 out, later LN2 out
    u16*  big    = (u16*)alloc((size_t)8192 * 4096 * 2);  // qkv, later mlp hidden
    u16*  attno  = (u16*)alloc((size_t)8192 * 1024 * 2);
    float* x2    = (float*)alloc((size_t)8192 * 1024 * 4);

    dim3 tb(32, 8);
    transpose_cast_kernel<<<dim3(3072 / 32, 1024 / 32), tb, 0, stream>>>(w_qkv,  wqkvT,  1024, 3072);
    transpose_cast_kernel<<<dim3(1024 / 32, 1024 / 32), tb, 0, stream>>>(w_proj, wprojT, 1024, 1024);
    transpose_cast_kernel<<<dim3(4096 / 32, 1024 / 32), tb, 0, stream>>>(w_fc1,  wfc1T,  1024, 4096);
    transpose_cast_kernel<<<dim3(1024 / 32, 4096 / 32), tb, 0, stream>>>(w_fc2,  wfc2T,  4096, 1024);

    ln_kernel<<<8192, 256, 0, stream>>>(x, ln1_g, ln1_b, hbuf);
    gemm_bt_kernel<MODE_BF16><<<dim3(3072 / 128, 8192 / 128), 256, 0, stream>>>(
        hbuf, wqkvT, b_qkv, nullptr, big, 8192, 3072, 1024);
    attn_kernel<<<2048, 256, 0, stream>>>(big, attno);
    gemm_bt_kernel<MODE_F32_RES><<<dim3(1024 / 128, 8192 / 128), 256, 0, stream>>>(
        attno, wprojT, b_proj, x, x2, 8192, 1024, 1024);
    ln_kernel<<<8192, 256, 0, stream>>>(x2, ln2_g, ln2_b, hbuf);
    gemm_bt_kernel<MODE_BF16_GELU><<<dim3(4096 / 128, 8192 / 128), 256, 0, stream>>>(
        hbuf, wfc1T, b_fc1, nullptr, big, 8192, 4096, 1024);
    gemm_bt_kernel<MODE_F32_RES><<<dim3(1024 / 128, 8192 / 128), 256, 0, stream>>>(
        big, wfc2T, b_fc2, x2, outp, 8192, 1024, 4096);
}

// Round 4
// 518.402 us; speedup vs baseline: 1.2509x; 1.1051x over previous
//
#include <hip/hip_runtime.h>
#include <cstdint>

// ---------------------------------------------------------------------------
// TransformerEncoderBlock: LN1 -> QKV -> MHA -> proj+res -> LN2 -> FC1+GELU
//                          -> FC2+res.  bf16 MFMA compute, fp32 accum.
// R4: fix vt indexing OOB (batch stride was 16384*1024 instead of 1024*1024,
//     writing ~250MB past the buffer and corrupting the harness's pristine
//     input copies -> post-timing divergence). Layout: vt[b][h*64+d][token].
// ---------------------------------------------------------------------------

typedef unsigned short u16;
typedef short short8 __attribute__((ext_vector_type(8)));   // 8 bf16 = 4 VGPRs
typedef float floatx4 __attribute__((ext_vector_type(4)));  // MFMA C/D

#define GLB(p) ((const __attribute__((address_space(1))) void*)(p))
#define LDSP(p) ((__attribute__((address_space(3))) void*)(p))

__device__ __forceinline__ u16 f2bf(float f) {
    uint32_t u = __float_as_uint(f);
    u += 0x7fffu + ((u >> 16) & 1u);   // round-to-nearest-even
    return (u16)(u >> 16);
}
__device__ __forceinline__ uint32_t pack2(float a, float b) {
    return (uint32_t)f2bf(a) | ((uint32_t)f2bf(b) << 16);
}

// ---------------- transpose + cast: W[K,N] f32 -> Wt[N,K] bf16 --------------
__global__ __launch_bounds__(256) void transpose_cast_kernel(
    const float* __restrict__ W, u16* __restrict__ Wt, int K, int N)
{
    __shared__ float tile[32][33];
    int n0 = blockIdx.x * 32, k0 = blockIdx.y * 32;
    int tx = threadIdx.x, ty = threadIdx.y; // block (32,8)
    #pragma unroll
    for (int i = 0; i < 4; ++i)
        tile[ty + i * 8][tx] = W[(size_t)(k0 + ty + i * 8) * N + n0 + tx];
    __syncthreads();
    #pragma unroll
    for (int i = 0; i < 4; ++i)
        Wt[(size_t)(n0 + ty + i * 8) * K + k0 + tx] = f2bf(tile[tx][ty + i * 8]);
}

// ---------------- LayerNorm: fp32 [rows,1024] -> bf16 ----------------------
__global__ __launch_bounds__(256) void ln_kernel(
    const float* __restrict__ x, const float* __restrict__ gw,
    const float* __restrict__ bw, u16* __restrict__ out)
{
    const int row = blockIdx.x, tid = threadIdx.x;
    float4 v = ((const float4*)(x + (size_t)row * 1024))[tid];
    float s  = v.x + v.y + v.z + v.w;
    float ss = v.x * v.x + v.y * v.y + v.z * v.z + v.w * v.w;
    #pragma unroll
    for (int off = 32; off > 0; off >>= 1) {
        s  += __shfl_down(s, off);
        ss += __shfl_down(ss, off);
    }
    __shared__ float red[8];
    if ((tid & 63) == 0) { red[tid >> 6] = s; red[4 + (tid >> 6)] = ss; }
    __syncthreads();
    float S  = red[0] + red[1] + red[2] + red[3];
    float SS = red[4] + red[5] + red[6] + red[7];
    float mu  = S * (1.0f / 1024.0f);
    float var = SS * (1.0f / 1024.0f) - mu * mu;
    float rs  = rsqrtf(var + 1e-5f);
    float4 g4 = ((const float4*)gw)[tid];
    float4 b4 = ((const float4*)bw)[tid];
    u16* o = out + (size_t)row * 1024 + tid * 4;
    o[0] = f2bf((v.x - mu) * rs * g4.x + b4.x);
    o[1] = f2bf((v.y - mu) * rs * g4.y + b4.y);
    o[2] = f2bf((v.z - mu) * rs * g4.z + b4.z);
    o[3] = f2bf((v.w - mu) * rs * g4.w + b4.w);
}

// ---------------- GEMM: C[M,N] = A[M,K](bf16) x Bt[N,K](bf16)^T ------------
// 128x128 tile, BK=64, 4 waves in 2x2, 4x4 16x16 C-tiles per wave.
// LDS rows: 8 chunks of 16B; physical chunk = logical ^ (row & 7).
#define MODE_BF16      0   // out bf16 = acc + bias
#define MODE_BF16_GELU 1   // out bf16 = gelu(acc + bias), exact erf gelu
#define MODE_F32_RES   2   // out f32  = acc + bias + res
#define MODE_QKV       3   // cols<2048: bf16 like MODE_BF16; cols>=2048: V^T to vt

template<int MODE>
__global__ __launch_bounds__(256) void gemm_bt_kernel(
    const u16* __restrict__ A, const u16* __restrict__ Bt,
    const float* __restrict__ bias, const float* __restrict__ res,
    void* __restrict__ outv, u16* __restrict__ vt, int M, int N, int K)
{
    __shared__ __attribute__((aligned(16))) u16 As[128 * 64];
    __shared__ __attribute__((aligned(16))) u16 Bs[128 * 64];
    const int tid = threadIdx.x;
    const int wave = tid >> 6, lane = tid & 63;
    const int lg = lane >> 4, lc = lane & 15;
    const int m0 = blockIdx.y * 128, n0 = blockIdx.x * 128;
    const int wr = wave >> 1, wc = wave & 1;

    floatx4 acc[4][4];
    #pragma unroll
    for (int i = 0; i < 4; ++i)
        #pragma unroll
        for (int j = 0; j < 4; ++j) acc[i][j] = floatx4{0.f, 0.f, 0.f, 0.f};

    const int srow = lane >> 3;                        // row & 7 within 8-row group
    const int schunk = (lane & 7) ^ srow;              // swizzled global chunk
    const u16* Ag = A  + (size_t)(m0 + wave * 32 + srow) * K + schunk * 8;
    const u16* Bg = Bt + (size_t)(n0 + wave * 32 + srow) * K + schunk * 8;
    u16* Asw = &As[wave * 4 * 512];   // wave-uniform LDS bases
    u16* Bsw = &Bs[wave * 4 * 512];

    const int kiters = K >> 6;
    for (int kt = 0; kt < kiters; ++kt) {
        #pragma unroll
        for (int j = 0; j < 4; ++j) {
            __builtin_amdgcn_global_load_lds(GLB(Ag + (size_t)j * 8 * K), LDSP(Asw + j * 512), 16, 0, 0);
            __builtin_amdgcn_global_load_lds(GLB(Bg + (size_t)j * 8 * K), LDSP(Bsw + j * 512), 16, 0, 0);
        }
        Ag += 64; Bg += 64;
        __syncthreads();
        #pragma unroll
        for (int ks = 0; ks < 2; ++ks) {
            short8 fa[4], fb[4];
            #pragma unroll
            for (int mt = 0; mt < 4; ++mt)
                fa[mt] = *(const short8*)&As[(wr * 64 + mt * 16 + lc) * 64 +
                                             (((ks * 4 + lg) ^ (lc & 7)) * 8)];
            #pragma unroll
            for (int nt = 0; nt < 4; ++nt)
                fb[nt] = *(const short8*)&Bs[(wc * 64 + nt * 16 + lc) * 64 +
                                             (((ks * 4 + lg) ^ (lc & 7)) * 8)];
            #pragma unroll
            for (int mt = 0; mt < 4; ++mt)
                #pragma unroll
                for (int nt = 0; nt < 4; ++nt)
                    acc[mt][nt] = __builtin_amdgcn_mfma_f32_16x16x32_bf16(fa[mt], fb[nt], acc[mt][nt], 0, 0, 0);
        }
        __syncthreads();
    }

    // epilogue: C/D layout col=lane&15, row=(lane>>4)*4+reg (HW-verified)
    if (MODE == MODE_QKV && n0 >= 2048) {
        // V columns -> vt[b][h*64+d][token], token contiguous (8B packed)
        #pragma unroll
        for (int mt = 0; mt < 4; ++mt) {
            #pragma unroll
            for (int nt = 0; nt < 4; ++nt) {
                const int col = n0 + wc * 64 + nt * 16 + lc;
                const float bv = bias[col];
                const int hd = col - 2048;         // h*64 + d
                const int rowbase = m0 + wr * 64 + mt * 16 + lg * 4;
                const int b = rowbase >> 10, token = rowbase & 1023;
                float v0 = acc[mt][nt][0] + bv, v1 = acc[mt][nt][1] + bv;
                float v2 = acc[mt][nt][2] + bv, v3 = acc[mt][nt][3] + bv;
                uint2 pk = {pack2(v0, v1), pack2(v2, v3)};
                *(uint2*)&vt[((size_t)b * 1024 + hd) * 1024 + token] = pk;
            }
        }
        return;
    }
    #pragma unroll
    for (int mt = 0; mt < 4; ++mt) {
        #pragma unroll
        for (int nt = 0; nt < 4; ++nt) {
            const int col = n0 + wc * 64 + nt * 16 + lc;
            const float bv = bias[col];
            #pragma unroll
            for (int r = 0; r < 4; ++r) {
                const int row = m0 + wr * 64 + mt * 16 + lg * 4 + r;
                float v = acc[mt][nt][r] + bv;
                if (MODE == MODE_BF16 || MODE == MODE_QKV) {
                    ((u16*)outv)[(size_t)row * N + col] = f2bf(v);
                } else if (MODE == MODE_BF16_GELU) {
                    float gl = 0.5f * v * (1.0f + erff(v * 0.70710678118f));
                    ((u16*)outv)[(size_t)row * N + col] = f2bf(gl);
                } else {
                    ((float*)outv)[(size_t)row * N + col] = v + res[(size_t)row * N + col];
                }
            }
        }
    }
}

// ---------------- Flash attention (S^T formulation) ------------------------
// qk buffer: [8,1024,3072] bf16 (Q at col 0, K at col 1024; V region unused)
// vtg: V^T [b][h*64+d][token] bf16.  Block = (b, head, 64-q tile); 4 waves.
// Per lane: q = wave*16 + (lane&15); keys/d live in regs via C-layout rows.
__global__ __launch_bounds__(256) void attn_kernel(
    const u16* __restrict__ qkv, const u16* __restrict__ vtg, u16* __restrict__ out)
{
    // XCD swizzle: the 16 q-tiles of one (b,h) share bid&7 -> same XCD L2
    const int bid = blockIdx.x;
    const int g = ((bid >> 7) << 3) | (bid & 7);   // (b,h) id, 0..127
    const int qt = (bid >> 3) & 15;
    const int h = g & 15, b = g >> 4;
    const int tid = threadIdx.x, wave = tid >> 6, lane = tid & 63;
    const int lg = lane >> 4, lc = lane & 15;

    __shared__ __attribute__((aligned(16))) u16 Qs[64 * 64];
    __shared__ __attribute__((aligned(16))) u16 Ks[64 * 64];
    __shared__ __attribute__((aligned(16))) u16 Vts[64 * 64]; // [d][key]
    __shared__ __attribute__((aligned(16))) u16 Ps[64 * 64];  // P^T rows q (wave-private)

    const int q0 = qt * 64;
    const size_t hb = ((size_t)b * 1024) * 3072 + h * 64;
    const u16* vhead = vtg + ((size_t)b * 1024 + h * 64) * 1024;
    const int srow = lane >> 3;
    const int schunk = (lane & 7) ^ srow;   // swizzled source chunk

    // stage Q tile [64 q][64 d]
    {
        const u16* Qg = qkv + hb + (size_t)(q0 + wave * 16 + srow) * 3072 + schunk * 8;
        u16* Qw = &Qs[wave * 1024];
        __builtin_amdgcn_global_load_lds(GLB(Qg), LDSP(Qw), 16, 0, 0);
        __builtin_amdgcn_global_load_lds(GLB(Qg + (size_t)8 * 3072), LDSP(Qw + 512), 16, 0, 0);
    }
    __syncthreads();
    short8 aq[2];   // B-operand: q = wave*16+lc, d = ks*32 + quad*8..+7
    aq[0] = *(const short8*)&Qs[(wave * 16 + lc) * 64 + (((0 + lg) ^ (lc & 7)) * 8)];
    aq[1] = *(const short8*)&Qs[(wave * 16 + lc) * 64 + (((4 + lg) ^ (lc & 7)) * 8)];

    floatx4 o[4];   // O^T tiles: d = dt*16 + lg*4 + r, q = wave*16+lc
    #pragma unroll
    for (int dt = 0; dt < 4; ++dt) o[dt] = floatx4{0.f, 0.f, 0.f, 0.f};
    float mprev = -INFINITY, lsum = 0.f;
    const float sc = 0.125f; // 1/sqrt(64)

    for (int kt = 0; kt < 16; ++kt) {
        __syncthreads();  // prior-iter readers of Ks/Vts done
        {   // stage K tile [64 key][64 d]
            const u16* Kg = qkv + hb + 1024 +
                (size_t)(kt * 64 + wave * 16 + srow) * 3072 + schunk * 8;
            u16* Kw = &Ks[wave * 1024];
            __builtin_amdgcn_global_load_lds(GLB(Kg), LDSP(Kw), 16, 0, 0);
            __builtin_amdgcn_global_load_lds(GLB(Kg + (size_t)8 * 3072), LDSP(Kw + 512), 16, 0, 0);
        }
        {   // stage V^T tile [64 d][64 key] straight from vtg
            const u16* Vg = vhead + (size_t)(wave * 16 + srow) * 1024 + kt * 64 + schunk * 8;
            u16* Vw = &Vts[wave * 1024];
            __builtin_amdgcn_global_load_lds(GLB(Vg), LDSP(Vw), 16, 0, 0);
            __builtin_amdgcn_global_load_lds(GLB(Vg + (size_t)8 * 1024), LDSP(Vw + 512), 16, 0, 0);
        }
        __syncthreads();

        // S^T = K Q^T : st[nt][r] -> key = nt*16 + lg*4 + r, q = wave*16+lc
        floatx4 st[4];
        #pragma unroll
        for (int nt = 0; nt < 4; ++nt) st[nt] = floatx4{0.f, 0.f, 0.f, 0.f};
        #pragma unroll
        for (int ks = 0; ks < 2; ++ks)
            #pragma unroll
            for (int nt = 0; nt < 4; ++nt) {
                short8 fk = *(const short8*)&Ks[(nt * 16 + lc) * 64 +
                                                (((ks * 4 + lg) ^ (lc & 7)) * 8)];
                st[nt] = __builtin_amdgcn_mfma_f32_16x16x32_bf16(fk, aq[ks], st[nt], 0, 0, 0);
            }

        // online softmax, scalar state per lane (one q per lane)
        float m = st[0][0];
        #pragma unroll
        for (int nt = 0; nt < 4; ++nt)
            #pragma unroll
            for (int r = 0; r < 4; ++r) m = fmaxf(m, st[nt][r]);
        m = fmaxf(m, __shfl_xor(m, 16));
        m = fmaxf(m, __shfl_xor(m, 32));
        float mn = fmaxf(mprev, m * sc);
        float aexp = __expf(mprev - mn);
        mprev = mn;

        const int q = wave * 16 + lc;
        float rs = 0.f;
        #pragma unroll
        for (int nt = 0; nt < 4; ++nt) {
            float p0 = __expf(st[nt][0] * sc - mn);
            float p1 = __expf(st[nt][1] * sc - mn);
            float p2 = __expf(st[nt][2] * sc - mn);
            float p3 = __expf(st[nt][3] * sc - mn);
            rs += (p0 + p1) + (p2 + p3);
            // P^T[q][key], keys nt*16 + lg*4 .. +3 contiguous -> b64 write
            const int c16 = nt * 2 + (lg >> 1);
            uint2 pk = {pack2(p0, p1), pack2(p2, p3)};
            *(uint2*)&Ps[q * 64 + ((c16 ^ (lc & 7)) * 8) + (lg & 1) * 4] = pk;
        }
        rs += __shfl_xor(rs, 16);
        rs += __shfl_xor(rs, 32);
        lsum = lsum * aexp + rs;
        #pragma unroll
        for (int dt = 0; dt < 4; ++dt)
            #pragma unroll
            for (int r = 0; r < 4; ++r) o[dt][r] *= aexp;

        // O^T += V^T P^T  (wave-private Ps rows -> no barrier)
        #pragma unroll
        for (int ks = 0; ks < 2; ++ks) {
            short8 fp = *(const short8*)&Ps[q * 64 + (((ks * 4 + lg) ^ (lc & 7)) * 8)];
            #pragma unroll
            for (int dt = 0; dt < 4; ++dt) {
                short8 fv = *(const short8*)&Vts[(dt * 16 + lc) * 64 +
                                                 (((ks * 4 + lg) ^ (lc & 7)) * 8)];
                o[dt] = __builtin_amdgcn_mfma_f32_16x16x32_bf16(fv, fp, o[dt], 0, 0, 0);
            }
        }
    }

    // epilogue: out[b, q, h*64 + d], d contiguous in r -> 8B packed stores
    const float rl = 1.0f / lsum;
    const int q = q0 + wave * 16 + lc;
    #pragma unroll
    for (int dt = 0; dt < 4; ++dt) {
        uint2 pk = {pack2(o[dt][0] * rl, o[dt][1] * rl),
                    pack2(o[dt][2] * rl, o[dt][3] * rl)};
        *(uint2*)&out[((size_t)b * 1024 + q) * 1024 + h * 64 + dt * 16 + lg * 4] = pk;
    }
}

// ---------------------------------------------------------------------------
extern "C" void kernel_launch(void* const* d_in, const int* in_sizes, int n_in,
                              void* d_out, int out_size, void* d_ws, size_t ws_size,
                              hipStream_t stream)
{
    const float* x      = (const float*)d_in[0];
    const float* ln1_g  = (const float*)d_in[1];
    const float* ln1_b  = (const float*)d_in[2];
    const float* w_qkv  = (const float*)d_in[3];
    const float* b_qkv  = (const float*)d_in[4];
    const float* w_proj = (const float*)d_in[5];
    const float* b_proj = (const float*)d_in[6];
    const float* ln2_g  = (const float*)d_in[7];
    const float* ln2_b  = (const float*)d_in[8];
    const float* w_fc1  = (const float*)d_in[9];
    const float* b_fc1  = (const float*)d_in[10];
    const float* w_fc2  = (const float*)d_in[11];
    const float* b_fc2  = (const float*)d_in[12];
    float* outp = (float*)d_out;

    char* ws = (char*)d_ws;
    size_t off = 0;
    auto alloc = [&](size_t bytes) { void* p = ws + off; off += (bytes + 255) & ~(size_t)255; return p; };
    u16*  wqkvT  = (u16*)alloc((size_t)3072 * 1024 * 2);
    u16*  wprojT = (u16*)alloc((size_t)1024 * 1024 * 2);
    u16*  wfc1T  = (u16*)alloc((size_t)4096 * 1024 * 2);
    u16*  wfc2T  = (u16*)alloc((size_t)1024 * 4096 * 2);
    u16*  hbuf   = (u16*)alloc((size_t)8192 * 1024 * 2);  // LN1 out, later LN2 out
    u16*  big    = (u16*)alloc((size_t)8192 * 4096 * 2);  // qk (stride 3072), later mlp hidden
    u16*  vtbuf  = (u16*)alloc((size_t)8 * 1024 * 1024 * 2); // V^T [b][h*64+d][token]
    u16*  attno  = (u16*)alloc((size_t)8192 * 1024 * 2);
    float* x2    = (float*)alloc((size_t)8192 * 1024 * 4);

    dim3 tb(32, 8);
    transpose_cast_kernel<<<dim3(3072 / 32, 1024 / 32), tb, 0, stream>>>(w_qkv,  wqkvT,  1024, 3072);
    transpose_cast_kernel<<<dim3(1024 / 32, 1024 / 32), tb, 0, stream>>>(w_proj, wprojT, 1024, 1024);
    transpose_cast_kernel<<<dim3(4096 / 32, 1024 / 32), tb, 0, stream>>>(w_fc1,  wfc1T,  1024, 4096);
    transpose_cast_kernel<<<dim3(1024 / 32, 4096 / 32), tb, 0, stream>>>(w_fc2,  wfc2T,  4096, 1024);

    ln_kernel<<<8192, 256, 0, stream>>>(x, ln1_g, ln1_b, hbuf);
    gemm_bt_kernel<MODE_QKV><<<dim3(3072 / 128, 8192 / 128), 256, 0, stream>>>(
        hbuf, wqkvT, b_qkv, nullptr, big, vtbuf, 8192, 3072, 1024);
    attn_kernel<<<2048, 256, 0, stream>>>(big, vtbuf, attno);
    gemm_bt_kernel<MODE_F32_RES><<<dim3(1024 / 128, 8192 / 128), 256, 0, stream>>>(
        attno, wprojT, b_proj, x, x2, nullptr, 8192, 1024, 1024);
    ln_kernel<<<8192, 256, 0, stream>>>(x2, ln2_g, ln2_b, hbuf);
    gemm_bt_kernel<MODE_BF16_GELU><<<dim3(4096 / 128, 8192 / 128), 256, 0, stream>>>(
        hbuf, wfc1T, b_fc1, nullptr, big, nullptr, 8192, 4096, 1024);
    gemm_bt_kernel<MODE_F32_RES><<<dim3(1024 / 128, 8192 / 128), 256, 0, stream>>>(
        big, wfc2T, b_fc2, x2, outp, nullptr, 8192, 1024, 4096);
}

// Round 5
// 510.544 us; speedup vs baseline: 1.2702x; 1.0154x over previous
//
#include <hip/hip_runtime.h>
#include <cstdint>

// ---------------------------------------------------------------------------
// TransformerEncoderBlock: LN1 -> QKV -> MHA -> proj+res -> LN2 -> FC1+GELU
//                          -> FC2+res.  bf16 MFMA compute, fp32 accum.
// R5: FC1 epilogue GELU erff -> tanh-approx (v_exp+v_rcp, branchless).
//     erff was ~2100 VALU instrs/thread (~40% of FC1 time; VALUBusy 68% vs
//     MfmaUtil 26%). tanh-approx error ~1e-3 pre-fc2 -> ~5e-4 at output.
// ---------------------------------------------------------------------------

typedef unsigned short u16;
typedef short short8 __attribute__((ext_vector_type(8)));   // 8 bf16 = 4 VGPRs
typedef float floatx4 __attribute__((ext_vector_type(4)));  // MFMA C/D

#define GLB(p) ((const __attribute__((address_space(1))) void*)(p))
#define LDSP(p) ((__attribute__((address_space(3))) void*)(p))

__device__ __forceinline__ u16 f2bf(float f) {
    uint32_t u = __float_as_uint(f);
    u += 0x7fffu + ((u >> 16) & 1u);   // round-to-nearest-even
    return (u16)(u >> 16);
}
__device__ __forceinline__ uint32_t pack2(float a, float b) {
    return (uint32_t)f2bf(a) | ((uint32_t)f2bf(b) << 16);
}
__device__ __forceinline__ float fast_gelu(float v) {
    // 0.5*v*(1+tanh(0.79788456*(v+0.044715 v^3))), tanh via exp+rcp, branchless
    float u = v * (0.7978845608f + 0.0356774081f * v * v);
    float e = __expf(2.0f * u);                       // v_exp_f32
    float th = 1.0f - 2.0f * __builtin_amdgcn_rcpf(e + 1.0f); // v_rcp_f32
    return 0.5f * v * (1.0f + th);
}

// ---------------- transpose + cast: W[K,N] f32 -> Wt[N,K] bf16 --------------
__global__ __launch_bounds__(256) void transpose_cast_kernel(
    const float* __restrict__ W, u16* __restrict__ Wt, int K, int N)
{
    __shared__ float tile[32][33];
    int n0 = blockIdx.x * 32, k0 = blockIdx.y * 32;
    int tx = threadIdx.x, ty = threadIdx.y; // block (32,8)
    #pragma unroll
    for (int i = 0; i < 4; ++i)
        tile[ty + i * 8][tx] = W[(size_t)(k0 + ty + i * 8) * N + n0 + tx];
    __syncthreads();
    #pragma unroll
    for (int i = 0; i < 4; ++i)
        Wt[(size_t)(n0 + ty + i * 8) * K + k0 + tx] = f2bf(tile[tx][ty + i * 8]);
}

// ---------------- LayerNorm: fp32 [rows,1024] -> bf16 ----------------------
__global__ __launch_bounds__(256) void ln_kernel(
    const float* __restrict__ x, const float* __restrict__ gw,
    const float* __restrict__ bw, u16* __restrict__ out)
{
    const int row = blockIdx.x, tid = threadIdx.x;
    float4 v = ((const float4*)(x + (size_t)row * 1024))[tid];
    float s  = v.x + v.y + v.z + v.w;
    float ss = v.x * v.x + v.y * v.y + v.z * v.z + v.w * v.w;
    #pragma unroll
    for (int off = 32; off > 0; off >>= 1) {
        s  += __shfl_down(s, off);
        ss += __shfl_down(ss, off);
    }
    __shared__ float red[8];
    if ((tid & 63) == 0) { red[tid >> 6] = s; red[4 + (tid >> 6)] = ss; }
    __syncthreads();
    float S  = red[0] + red[1] + red[2] + red[3];
    float SS = red[4] + red[5] + red[6] + red[7];
    float mu  = S * (1.0f / 1024.0f);
    float var = SS * (1.0f / 1024.0f) - mu * mu;
    float rs  = rsqrtf(var + 1e-5f);
    float4 g4 = ((const float4*)gw)[tid];
    float4 b4 = ((const float4*)bw)[tid];
    u16* o = out + (size_t)row * 1024 + tid * 4;
    o[0] = f2bf((v.x - mu) * rs * g4.x + b4.x);
    o[1] = f2bf((v.y - mu) * rs * g4.y + b4.y);
    o[2] = f2bf((v.z - mu) * rs * g4.z + b4.z);
    o[3] = f2bf((v.w - mu) * rs * g4.w + b4.w);
}

// ---------------- GEMM: C[M,N] = A[M,K](bf16) x Bt[N,K](bf16)^T ------------
// 128x128 tile, BK=64, 4 waves in 2x2, 4x4 16x16 C-tiles per wave.
// LDS rows: 8 chunks of 16B; physical chunk = logical ^ (row & 7).
#define MODE_BF16      0   // out bf16 = acc + bias
#define MODE_BF16_GELU 1   // out bf16 = gelu(acc + bias), tanh-approx gelu
#define MODE_F32_RES   2   // out f32  = acc + bias + res
#define MODE_QKV       3   // cols<2048: bf16 like MODE_BF16; cols>=2048: V^T to vt

template<int MODE>
__global__ __launch_bounds__(256) void gemm_bt_kernel(
    const u16* __restrict__ A, const u16* __restrict__ Bt,
    const float* __restrict__ bias, const float* __restrict__ res,
    void* __restrict__ outv, u16* __restrict__ vt, int M, int N, int K)
{
    __shared__ __attribute__((aligned(16))) u16 As[128 * 64];
    __shared__ __attribute__((aligned(16))) u16 Bs[128 * 64];
    const int tid = threadIdx.x;
    const int wave = tid >> 6, lane = tid & 63;
    const int lg = lane >> 4, lc = lane & 15;
    const int m0 = blockIdx.y * 128, n0 = blockIdx.x * 128;
    const int wr = wave >> 1, wc = wave & 1;

    floatx4 acc[4][4];
    #pragma unroll
    for (int i = 0; i < 4; ++i)
        #pragma unroll
        for (int j = 0; j < 4; ++j) acc[i][j] = floatx4{0.f, 0.f, 0.f, 0.f};

    const int srow = lane >> 3;                        // row & 7 within 8-row group
    const int schunk = (lane & 7) ^ srow;              // swizzled global chunk
    const u16* Ag = A  + (size_t)(m0 + wave * 32 + srow) * K + schunk * 8;
    const u16* Bg = Bt + (size_t)(n0 + wave * 32 + srow) * K + schunk * 8;
    u16* Asw = &As[wave * 4 * 512];   // wave-uniform LDS bases
    u16* Bsw = &Bs[wave * 4 * 512];

    const int kiters = K >> 6;
    for (int kt = 0; kt < kiters; ++kt) {
        #pragma unroll
        for (int j = 0; j < 4; ++j) {
            __builtin_amdgcn_global_load_lds(GLB(Ag + (size_t)j * 8 * K), LDSP(Asw + j * 512), 16, 0, 0);
            __builtin_amdgcn_global_load_lds(GLB(Bg + (size_t)j * 8 * K), LDSP(Bsw + j * 512), 16, 0, 0);
        }
        Ag += 64; Bg += 64;
        __syncthreads();
        #pragma unroll
        for (int ks = 0; ks < 2; ++ks) {
            short8 fa[4], fb[4];
            #pragma unroll
            for (int mt = 0; mt < 4; ++mt)
                fa[mt] = *(const short8*)&As[(wr * 64 + mt * 16 + lc) * 64 +
                                             (((ks * 4 + lg) ^ (lc & 7)) * 8)];
            #pragma unroll
            for (int nt = 0; nt < 4; ++nt)
                fb[nt] = *(const short8*)&Bs[(wc * 64 + nt * 16 + lc) * 64 +
                                             (((ks * 4 + lg) ^ (lc & 7)) * 8)];
            #pragma unroll
            for (int mt = 0; mt < 4; ++mt)
                #pragma unroll
                for (int nt = 0; nt < 4; ++nt)
                    acc[mt][nt] = __builtin_amdgcn_mfma_f32_16x16x32_bf16(fa[mt], fb[nt], acc[mt][nt], 0, 0, 0);
        }
        __syncthreads();
    }

    // epilogue: C/D layout col=lane&15, row=(lane>>4)*4+reg (HW-verified)
    if (MODE == MODE_QKV && n0 >= 2048) {
        // V columns -> vt[b][h*64+d][token], token contiguous (8B packed)
        #pragma unroll
        for (int mt = 0; mt < 4; ++mt) {
            #pragma unroll
            for (int nt = 0; nt < 4; ++nt) {
                const int col = n0 + wc * 64 + nt * 16 + lc;
                const float bv = bias[col];
                const int hd = col - 2048;         // h*64 + d
                const int rowbase = m0 + wr * 64 + mt * 16 + lg * 4;
                const int b = rowbase >> 10, token = rowbase & 1023;
                float v0 = acc[mt][nt][0] + bv, v1 = acc[mt][nt][1] + bv;
                float v2 = acc[mt][nt][2] + bv, v3 = acc[mt][nt][3] + bv;
                uint2 pk = {pack2(v0, v1), pack2(v2, v3)};
                *(uint2*)&vt[((size_t)b * 1024 + hd) * 1024 + token] = pk;
            }
        }
        return;
    }
    #pragma unroll
    for (int mt = 0; mt < 4; ++mt) {
        #pragma unroll
        for (int nt = 0; nt < 4; ++nt) {
            const int col = n0 + wc * 64 + nt * 16 + lc;
            const float bv = bias[col];
            #pragma unroll
            for (int r = 0; r < 4; ++r) {
                const int row = m0 + wr * 64 + mt * 16 + lg * 4 + r;
                float v = acc[mt][nt][r] + bv;
                if (MODE == MODE_BF16 || MODE == MODE_QKV) {
                    ((u16*)outv)[(size_t)row * N + col] = f2bf(v);
                } else if (MODE == MODE_BF16_GELU) {
                    ((u16*)outv)[(size_t)row * N + col] = f2bf(fast_gelu(v));
                } else {
                    ((float*)outv)[(size_t)row * N + col] = v + res[(size_t)row * N + col];
                }
            }
        }
    }
}

// ---------------- Flash attention (S^T formulation) ------------------------
// qk buffer: [8,1024,3072] bf16 (Q at col 0, K at col 1024; V region unused)
// vtg: V^T [b][h*64+d][token] bf16.  Block = (b, head, 64-q tile); 4 waves.
// Per lane: q = wave*16 + (lane&15); keys/d live in regs via C-layout rows.
__global__ __launch_bounds__(256) void attn_kernel(
    const u16* __restrict__ qkv, const u16* __restrict__ vtg, u16* __restrict__ out)
{
    // XCD swizzle: the 16 q-tiles of one (b,h) share bid&7 -> same XCD L2
    const int bid = blockIdx.x;
    const int g = ((bid >> 7) << 3) | (bid & 7);   // (b,h) id, 0..127
    const int qt = (bid >> 3) & 15;
    const int h = g & 15, b = g >> 4;
    const int tid = threadIdx.x, wave = tid >> 6, lane = tid & 63;
    const int lg = lane >> 4, lc = lane & 15;

    __shared__ __attribute__((aligned(16))) u16 Qs[64 * 64];
    __shared__ __attribute__((aligned(16))) u16 Ks[64 * 64];
    __shared__ __attribute__((aligned(16))) u16 Vts[64 * 64]; // [d][key]
    __shared__ __attribute__((aligned(16))) u16 Ps[64 * 64];  // P^T rows q (wave-private)

    const int q0 = qt * 64;
    const size_t hb = ((size_t)b * 1024) * 3072 + h * 64;
    const u16* vhead = vtg + ((size_t)b * 1024 + h * 64) * 1024;
    const int srow = lane >> 3;
    const int schunk = (lane & 7) ^ srow;   // swizzled source chunk

    // stage Q tile [64 q][64 d]
    {
        const u16* Qg = qkv + hb + (size_t)(q0 + wave * 16 + srow) * 3072 + schunk * 8;
        u16* Qw = &Qs[wave * 1024];
        __builtin_amdgcn_global_load_lds(GLB(Qg), LDSP(Qw), 16, 0, 0);
        __builtin_amdgcn_global_load_lds(GLB(Qg + (size_t)8 * 3072), LDSP(Qw + 512), 16, 0, 0);
    }
    __syncthreads();
    short8 aq[2];   // B-operand: q = wave*16+lc, d = ks*32 + quad*8..+7
    aq[0] = *(const short8*)&Qs[(wave * 16 + lc) * 64 + (((0 + lg) ^ (lc & 7)) * 8)];
    aq[1] = *(const short8*)&Qs[(wave * 16 + lc) * 64 + (((4 + lg) ^ (lc & 7)) * 8)];

    floatx4 o[4];   // O^T tiles: d = dt*16 + lg*4 + r, q = wave*16+lc
    #pragma unroll
    for (int dt = 0; dt < 4; ++dt) o[dt] = floatx4{0.f, 0.f, 0.f, 0.f};
    float mprev = -INFINITY, lsum = 0.f;
    const float sc = 0.125f; // 1/sqrt(64)

    for (int kt = 0; kt < 16; ++kt) {
        __syncthreads();  // prior-iter readers of Ks/Vts done
        {   // stage K tile [64 key][64 d]
            const u16* Kg = qkv + hb + 1024 +
                (size_t)(kt * 64 + wave * 16 + srow) * 3072 + schunk * 8;
            u16* Kw = &Ks[wave * 1024];
            __builtin_amdgcn_global_load_lds(GLB(Kg), LDSP(Kw), 16, 0, 0);
            __builtin_amdgcn_global_load_lds(GLB(Kg + (size_t)8 * 3072), LDSP(Kw + 512), 16, 0, 0);
        }
        {   // stage V^T tile [64 d][64 key] straight from vtg
            const u16* Vg = vhead + (size_t)(wave * 16 + srow) * 1024 + kt * 64 + schunk * 8;
            u16* Vw = &Vts[wave * 1024];
            __builtin_amdgcn_global_load_lds(GLB(Vg), LDSP(Vw), 16, 0, 0);
            __builtin_amdgcn_global_load_lds(GLB(Vg + (size_t)8 * 1024), LDSP(Vw + 512), 16, 0, 0);
        }
        __syncthreads();

        // S^T = K Q^T : st[nt][r] -> key = nt*16 + lg*4 + r, q = wave*16+lc
        floatx4 st[4];
        #pragma unroll
        for (int nt = 0; nt < 4; ++nt) st[nt] = floatx4{0.f, 0.f, 0.f, 0.f};
        #pragma unroll
        for (int ks = 0; ks < 2; ++ks)
            #pragma unroll
            for (int nt = 0; nt < 4; ++nt) {
                short8 fk = *(const short8*)&Ks[(nt * 16 + lc) * 64 +
                                                (((ks * 4 + lg) ^ (lc & 7)) * 8)];
                st[nt] = __builtin_amdgcn_mfma_f32_16x16x32_bf16(fk, aq[ks], st[nt], 0, 0, 0);
            }

        // online softmax, scalar state per lane (one q per lane)
        float m = st[0][0];
        #pragma unroll
        for (int nt = 0; nt < 4; ++nt)
            #pragma unroll
            for (int r = 0; r < 4; ++r) m = fmaxf(m, st[nt][r]);
        m = fmaxf(m, __shfl_xor(m, 16));
        m = fmaxf(m, __shfl_xor(m, 32));
        float mn = fmaxf(mprev, m * sc);
        float aexp = __expf(mprev - mn);
        mprev = mn;

        const int q = wave * 16 + lc;
        float rs = 0.f;
        #pragma unroll
        for (int nt = 0; nt < 4; ++nt) {
            float p0 = __expf(st[nt][0] * sc - mn);
            float p1 = __expf(st[nt][1] * sc - mn);
            float p2 = __expf(st[nt][2] * sc - mn);
            float p3 = __expf(st[nt][3] * sc - mn);
            rs += (p0 + p1) + (p2 + p3);
            // P^T[q][key], keys nt*16 + lg*4 .. +3 contiguous -> b64 write
            const int c16 = nt * 2 + (lg >> 1);
            uint2 pk = {pack2(p0, p1), pack2(p2, p3)};
            *(uint2*)&Ps[q * 64 + ((c16 ^ (lc & 7)) * 8) + (lg & 1) * 4] = pk;
        }
        rs += __shfl_xor(rs, 16);
        rs += __shfl_xor(rs, 32);
        lsum = lsum * aexp + rs;
        #pragma unroll
        for (int dt = 0; dt < 4; ++dt)
            #pragma unroll
            for (int r = 0; r < 4; ++r) o[dt][r] *= aexp;

        // O^T += V^T P^T  (wave-private Ps rows -> no barrier)
        #pragma unroll
        for (int ks = 0; ks < 2; ++ks) {
            short8 fp = *(const short8*)&Ps[q * 64 + (((ks * 4 + lg) ^ (lc & 7)) * 8)];
            #pragma unroll
            for (int dt = 0; dt < 4; ++dt) {
                short8 fv = *(const short8*)&Vts[(dt * 16 + lc) * 64 +
                                                 (((ks * 4 + lg) ^ (lc & 7)) * 8)];
                o[dt] = __builtin_amdgcn_mfma_f32_16x16x32_bf16(fv, fp, o[dt], 0, 0, 0);
            }
        }
    }

    // epilogue: out[b, q, h*64 + d], d contiguous in r -> 8B packed stores
    const float rl = 1.0f / lsum;
    const int q = q0 + wave * 16 + lc;
    #pragma unroll
    for (int dt = 0; dt < 4; ++dt) {
        uint2 pk = {pack2(o[dt][0] * rl, o[dt][1] * rl),
                    pack2(o[dt][2] * rl, o[dt][3] * rl)};
        *(uint2*)&out[((size_t)b * 1024 + q) * 1024 + h * 64 + dt * 16 + lg * 4] = pk;
    }
}

// ---------------------------------------------------------------------------
extern "C" void kernel_launch(void* const* d_in, const int* in_sizes, int n_in,
                              void* d_out, int out_size, void* d_ws, size_t ws_size,
                              hipStream_t stream)
{
    const float* x      = (const float*)d_in[0];
    const float* ln1_g  = (const float*)d_in[1];
    const float* ln1_b  = (const float*)d_in[2];
    const float* w_qkv  = (const float*)d_in[3];
    const float* b_qkv  = (const float*)d_in[4];
    const float* w_proj = (const float*)d_in[5];
    const float* b_proj = (const float*)d_in[6];
    const float* ln2_g  = (const float*)d_in[7];
    const float* ln2_b  = (const float*)d_in[8];
    const float* w_fc1  = (const float*)d_in[9];
    const float* b_fc1  = (const float*)d_in[10];
    const float* w_fc2  = (const float*)d_in[11];
    const float* b_fc2  = (const float*)d_in[12];
    float* outp = (float*)d_out;

    char* ws = (char*)d_ws;
    size_t off = 0;
    auto alloc = [&](size_t bytes) { void* p = ws + off; off += (bytes + 255) & ~(size_t)255; return p; };
    u16*  wqkvT  = (u16*)alloc((size_t)3072 * 1024 * 2);
    u16*  wprojT = (u16*)alloc((size_t)1024 * 1024 * 2);
    u16*  wfc1T  = (u16*)alloc((size_t)4096 * 1024 * 2);
    u16*  wfc2T  = (u16*)alloc((size_t)1024 * 4096 * 2);
    u16*  hbuf   = (u16*)alloc((size_t)8192 * 1024 * 2);  // LN1 out, later LN2 out
    u16*  big    = (u16*)alloc((size_t)8192 * 4096 * 2);  // qk (stride 3072), later mlp hidden
    u16*  vtbuf  = (u16*)alloc((size_t)8 * 1024 * 1024 * 2); // V^T [b][h*64+d][token]
    u16*  attno  = (u16*)alloc((size_t)8192 * 1024 * 2);
    float* x2    = (float*)alloc((size_t)8192 * 1024 * 4);

    dim3 tb(32, 8);
    transpose_cast_kernel<<<dim3(3072 / 32, 1024 / 32), tb, 0, stream>>>(w_qkv,  wqkvT,  1024, 3072);
    transpose_cast_kernel<<<dim3(1024 / 32, 1024 / 32), tb, 0, stream>>>(w_proj, wprojT, 1024, 1024);
    transpose_cast_kernel<<<dim3(4096 / 32, 1024 / 32), tb, 0, stream>>>(w_fc1,  wfc1T,  1024, 4096);
    transpose_cast_kernel<<<dim3(1024 / 32, 4096 / 32), tb, 0, stream>>>(w_fc2,  wfc2T,  4096, 1024);

    ln_kernel<<<8192, 256, 0, stream>>>(x, ln1_g, ln1_b, hbuf);
    gemm_bt_kernel<MODE_QKV><<<dim3(3072 / 128, 8192 / 128), 256, 0, stream>>>(
        hbuf, wqkvT, b_qkv, nullptr, big, vtbuf, 8192, 3072, 1024);
    attn_kernel<<<2048, 256, 0, stream>>>(big, vtbuf, attno);
    gemm_bt_kernel<MODE_F32_RES><<<dim3(1024 / 128, 8192 / 128), 256, 0, stream>>>(
        attno, wprojT, b_proj, x, x2, nullptr, 8192, 1024, 1024);
    ln_kernel<<<8192, 256, 0, stream>>>(x2, ln2_g, ln2_b, hbuf);
    gemm_bt_kernel<MODE_BF16_GELU><<<dim3(4096 / 128, 8192 / 128), 256, 0, stream>>>(
        hbuf, wfc1T, b_fc1, nullptr, big, nullptr, 8192, 4096, 1024);
    gemm_bt_kernel<MODE_F32_RES><<<dim3(1024 / 128, 8192 / 128), 256, 0, stream>>>(
        big, wfc2T, b_fc2, x2, outp, nullptr, 8192, 1024, 4096);
}